// Round 8
// baseline (308.345 us; speedup 1.0000x reference)
//
#include <hip/hip_runtime.h>

#define DD 128
#define NN 50000      // nodes (N)
#define BB 2          // batch
#define EE 500000     // edges
#define RR 500        // relations
#define LN_EPS 1e-5f

typedef __attribute__((ext_vector_type(8))) short bf16x8;
typedef __attribute__((ext_vector_type(16))) float f32x16;

union FragU { unsigned short u[8]; bf16x8 v; };

__device__ __forceinline__ unsigned short f2bf(float x) {
  union { float f; unsigned u; } v; v.f = x;
  unsigned r = (v.u + 0x7FFFu + ((v.u >> 16) & 1u)) >> 16;
  return (unsigned short)r;
}

// packed fp32x2 -> bf16x2 (1 VALU op on gfx950; manual RNE fallback)
#if defined(__has_builtin)
#if __has_builtin(__builtin_amdgcn_cvt_pk_bf16_f32)
#define HAVE_PK_BF16 1
#endif
#endif
__device__ __forceinline__ unsigned pk2bf(float a, float b) {
#ifdef HAVE_PK_BF16
  typedef __attribute__((ext_vector_type(2))) __bf16 bf16x2_t;
  union { bf16x2_t v; unsigned u; } c;
  c.v = __builtin_amdgcn_cvt_pk_bf16_f32(a, b);
  return c.u;
#else
  return (unsigned)f2bf(a) | ((unsigned)f2bf(b) << 16);
#endif
}

__device__ __forceinline__ float bfbits(unsigned short s) {
  union { unsigned u; float f; } v;
  v.u = ((unsigned)s) << 16;
  return v.f;
}
__device__ __forceinline__ float sigmoidf(float x) {
  return 1.0f / (1.0f + __expf(-x));
}

// ---------------------------------------------------------------------------
// k_prep: zero deg; rel_emb -> bf16; transpose+convert all 3 weight mats to
// bf16 [f][k] so GEMM A-frag preloads are contiguous b128 (no strided dwords,
// no converts in the hot kernels).
// ---------------------------------------------------------------------------
__global__ __launch_bounds__(256) void k_prep(
    const float* __restrict__ rel_emb, const float* __restrict__ gate_W,
    const float* __restrict__ msg_W, const float* __restrict__ upd_W,
    unsigned short* __restrict__ relb, unsigned short* __restrict__ gateT,
    unsigned short* __restrict__ msgT, unsigned short* __restrict__ updT,
    int* __restrict__ deg)
{
  const int id = blockIdx.x * 256 + threadIdx.x;
  if (id < RR * DD / 2)
    *(unsigned*)&relb[2 * id] = pk2bf(rel_emb[2 * id], rel_emb[2 * id + 1]);
  if (id < NN) deg[id] = 0;
  if (id < 128 * 64) {               // gate + msg: f = id>>6, k2 = id&63
    const int f = id >> 6, k2 = id & 63;
    *(unsigned*)&gateT[f * 128 + 2 * k2] =
        pk2bf(gate_W[(2 * k2) * DD + f], gate_W[(2 * k2 + 1) * DD + f]);
    *(unsigned*)&msgT[f * 128 + 2 * k2] =
        pk2bf(msg_W[(2 * k2) * DD + f], msg_W[(2 * k2 + 1) * DD + f]);
  }
  if (id < 128 * 128) {              // upd: f = id>>7, k2 = id&127 (K=256)
    const int f = id >> 7, k2 = id & 127;
    *(unsigned*)&updT[f * 256 + 2 * k2] =
        pk2bf(upd_W[(2 * k2) * DD + f], upd_W[(2 * k2 + 1) * DD + f]);
  }
}

// ---------------------------------------------------------------------------
// Kernel 1: node dual-GEMM, 32x32x16 MFMA, weights register-resident
// (b128 loads from pre-transposed gateT/msgT). P staged through parity
// double-buffered LDS -> full-128B-line cooperative stores, ONE barrier/tile.
// ---------------------------------------------------------------------------
__global__ __launch_bounds__(256) void k_node(
    const float* __restrict__ h, const unsigned short* __restrict__ gateT,
    const unsigned short* __restrict__ msgT, unsigned short* __restrict__ P,
    int BN)
{
  __shared__ unsigned short Ps[2][32][132];   // parity buffers, stride 132

  const int t    = threadIdx.x;
  const int w    = t >> 6;        // wave -> feature strip [32w, 32w+32)
  const int lane = t & 63;
  const int n32  = lane & 31;
  const int hi   = lane >> 5;
  const int f    = w * 32 + n32;  // A-operand row m

  // A-frags: 16 contiguous b128 loads, no converts
  bf16x8 ag[8], am[8];
#pragma unroll
  for (int ks = 0; ks < 8; ks++) {
    ag[ks] = *(const bf16x8*)&gateT[f * 128 + ks * 16 + hi * 8];
    am[ks] = *(const bf16x8*)&msgT [f * 128 + ks * 16 + hi * 8];
  }

  const int nodeL = t >> 3;       // store phase: node 0..31
  const int ch    = t & 7;        // 16B chunk 0..7

  const int nT = BN >> 5;
  int par = 0;
  for (int tile = blockIdx.x; tile < nT; tile += gridDim.x, par ^= 1) {
    const int row  = tile * 32 + n32;
    const size_t hoff = (size_t)row * DD + hi * 8;

    FragU bf[8];
#pragma unroll
    for (int ks = 0; ks < 8; ks++) {
      const float4 x0 = *(const float4*)(h + hoff + ks * 16);
      const float4 x1 = *(const float4*)(h + hoff + ks * 16 + 4);
      *(unsigned*)&bf[ks].u[0] = pk2bf(x0.x, x0.y);
      *(unsigned*)&bf[ks].u[2] = pk2bf(x0.z, x0.w);
      *(unsigned*)&bf[ks].u[4] = pk2bf(x1.x, x1.y);
      *(unsigned*)&bf[ks].u[6] = pk2bf(x1.z, x1.w);
    }

    f32x16 accg = (f32x16)0.f, accm = (f32x16)0.f;
#pragma unroll
    for (int ks = 0; ks < 8; ks++) {
      accg = __builtin_amdgcn_mfma_f32_32x32x16_bf16(ag[ks], bf[ks].v, accg, 0, 0, 0);
      accm = __builtin_amdgcn_mfma_f32_32x32x16_bf16(am[ks], bf[ks].v, accm, 0, 0, 0);
    }

    // stage into LDS: node n32, features f = 32w + 8q + 4hi + i
    unsigned short* Lr = &Ps[par][n32][w * 32 + hi * 4];
#pragma unroll
    for (int q = 0; q < 4; q++) {
      const float v0 = accm[q * 4 + 0] * sigmoidf(accg[q * 4 + 0]);
      const float v1 = accm[q * 4 + 1] * sigmoidf(accg[q * 4 + 1]);
      const float v2 = accm[q * 4 + 2] * sigmoidf(accg[q * 4 + 2]);
      const float v3 = accm[q * 4 + 3] * sigmoidf(accg[q * 4 + 3]);
      uint2 o;
      o.x = pk2bf(v0, v1);
      o.y = pk2bf(v2, v3);
      *(uint2*)(Lr + q * 8) = o;
    }
    __syncthreads();   // single barrier: parity buffer isolates iterations

    // coalesced store: thread t -> node = t>>3, 2 x 16B chunks, full lines
    const int grow = tile * 32 + nodeL;
    const int bS   = (grow >= NN) ? 1 : 0;
    unsigned short* gp = P + (size_t)(grow - bS * NN) * 256 + bS * 128;
    *(uint4*)(gp + ch * 8)       = *(uint4*)&Ps[par][nodeL][ch * 8];
    *(uint4*)(gp + (ch + 8) * 8) = *(uint4*)&Ps[par][nodeL][(ch + 8) * 8];
  }
}

// ---------------------------------------------------------------------------
// CSR build: histogram -> block scans -> fill (counting sort by target).
// ---------------------------------------------------------------------------
__global__ __launch_bounds__(256) void k_hist(
    const int* __restrict__ etgt, int* __restrict__ deg)
{
  const int e = blockIdx.x * 256 + threadIdx.x;
  if (e < EE) atomicAdd(&deg[etgt[e]], 1);
}

__global__ __launch_bounds__(256) void k_scan_block(
    const int* __restrict__ deg, int* __restrict__ rstart,
    int* __restrict__ bsum, int N)
{
  __shared__ int s[256];
  const int i = blockIdx.x * 256 + threadIdx.x;
  const int v = (i < N) ? deg[i] : 0;
  s[threadIdx.x] = v;
  __syncthreads();
#pragma unroll
  for (int off = 1; off < 256; off <<= 1) {
    const int tv = (threadIdx.x >= off) ? s[threadIdx.x - off] : 0;
    __syncthreads();
    s[threadIdx.x] += tv;
    __syncthreads();
  }
  if (i < N) rstart[i] = s[threadIdx.x] - v;
  if (threadIdx.x == 255) bsum[blockIdx.x] = s[255];
}

__global__ __launch_bounds__(256) void k_scan_small(
    int* __restrict__ bsum, int* __restrict__ boff, int nb)
{
  __shared__ int s[256];
  const int v = (threadIdx.x < nb) ? bsum[threadIdx.x] : 0;
  s[threadIdx.x] = v;
  __syncthreads();
#pragma unroll
  for (int off = 1; off < 256; off <<= 1) {
    const int tv = (threadIdx.x >= off) ? s[threadIdx.x - off] : 0;
    __syncthreads();
    s[threadIdx.x] += tv;
    __syncthreads();
  }
  if (threadIdx.x < nb) boff[threadIdx.x] = s[threadIdx.x] - v;
}

__global__ __launch_bounds__(256) void k_add_off(
    int* __restrict__ rstart, const int* __restrict__ boff,
    int* __restrict__ cur, int N)
{
  const int i = blockIdx.x * 256 + threadIdx.x;
  if (i < N) {
    const int v = rstart[i] + boff[blockIdx.x];
    rstart[i] = v;
    cur[i] = v;
  }
}

__global__ __launch_bounds__(256) void k_fill(
    const int* __restrict__ esrc, const int* __restrict__ etgt,
    const int* __restrict__ erel, int* __restrict__ cur,
    int* __restrict__ packed)
{
  const int e = blockIdx.x * 256 + threadIdx.x;
  if (e < EE) {
    const int pos = atomicAdd(&cur[etgt[e]], 1);
    packed[pos] = esrc[e] | (erel[e] << 16);
  }
}

// ---------------------------------------------------------------------------
// Kernel 2: gather aggregation. One wave per node; half-wave per edge,
// 4x unrolled => 16 independent 16B loads in flight per wave.
// ---------------------------------------------------------------------------
__global__ __launch_bounds__(256) void k_agg(
    const unsigned short* __restrict__ P, const unsigned short* __restrict__ relb,
    const int* __restrict__ rstart, const int* __restrict__ packed,
    unsigned short* __restrict__ h_agg)
{
  const int node = blockIdx.x * 4 + (threadIdx.x >> 6);
  if (node >= NN) return;
  const int lane = threadIdx.x & 63;
  const int half = lane >> 5;
  const int c8   = (lane & 31) * 8;
  const int rc   = c8 & 127;

  const int beg = rstart[node];
  const int end = (node == NN - 1) ? EE : rstart[node + 1];

  float acc[8];
#pragma unroll
  for (int i = 0; i < 8; i++) acc[i] = 0.f;

  int j = beg + half;
  for (; j + 6 < end; j += 8) {      // 4 edges per half in flight
    const int p0 = packed[j];
    const int p1 = packed[j + 2];
    const int p2 = packed[j + 4];
    const int p3 = packed[j + 6];
    const bf16x8 pv0 = *(const bf16x8*)(P + (size_t)(p0 & 0xFFFF) * 256 + c8);
    const bf16x8 rv0 = *(const bf16x8*)(relb + (size_t)(p0 >> 16) * DD + rc);
    const bf16x8 pv1 = *(const bf16x8*)(P + (size_t)(p1 & 0xFFFF) * 256 + c8);
    const bf16x8 rv1 = *(const bf16x8*)(relb + (size_t)(p1 >> 16) * DD + rc);
    const bf16x8 pv2 = *(const bf16x8*)(P + (size_t)(p2 & 0xFFFF) * 256 + c8);
    const bf16x8 rv2 = *(const bf16x8*)(relb + (size_t)(p2 >> 16) * DD + rc);
    const bf16x8 pv3 = *(const bf16x8*)(P + (size_t)(p3 & 0xFFFF) * 256 + c8);
    const bf16x8 rv3 = *(const bf16x8*)(relb + (size_t)(p3 >> 16) * DD + rc);
#pragma unroll
    for (int i = 0; i < 8; i++) {
      acc[i] += bfbits(pv0[i]) * bfbits(rv0[i]);
      acc[i] += bfbits(pv1[i]) * bfbits(rv1[i]);
      acc[i] += bfbits(pv2[i]) * bfbits(rv2[i]);
      acc[i] += bfbits(pv3[i]) * bfbits(rv3[i]);
    }
  }
  for (; j < end; j += 2) {
    const int p0 = packed[j];
    const bf16x8 pv0 = *(const bf16x8*)(P + (size_t)(p0 & 0xFFFF) * 256 + c8);
    const bf16x8 rv0 = *(const bf16x8*)(relb + (size_t)(p0 >> 16) * DD + rc);
#pragma unroll
    for (int i = 0; i < 8; i++) acc[i] += bfbits(pv0[i]) * bfbits(rv0[i]);
  }

#pragma unroll
  for (int i = 0; i < 8; i++) acc[i] += __shfl_xor(acc[i], 32, 64);

  if (half == 0) {
    uint4 o;
    o.x = pk2bf(acc[0], acc[1]);
    o.y = pk2bf(acc[2], acc[3]);
    o.z = pk2bf(acc[4], acc[5]);
    o.w = pk2bf(acc[6], acc[7]);
    *(uint4*)(h_agg + (size_t)node * 256 + c8) = o;
  }
}

// ---------------------------------------------------------------------------
// Kernel 3: update GEMM (K=256), 32x32x16 MFMA, register weights (b128 from
// updT). B-frags: k<128 from fp32 h (packed cvt), k>=128 from h_agg (bf16).
// fp32 residual. Full-line out stores.
// ---------------------------------------------------------------------------
__global__ __launch_bounds__(256) void k_update_ln(
    const float* __restrict__ h, const unsigned short* __restrict__ h_agg,
    const unsigned short* __restrict__ updT, const float* __restrict__ upd_b,
    const float* __restrict__ gamma, const float* __restrict__ beta,
    float* __restrict__ out, int BN)
{
  __shared__ float2 red[2][4][32];

  const int t    = threadIdx.x;
  const int w    = t >> 6;
  const int lane = t & 63;
  const int n32  = lane & 31;
  const int hi   = lane >> 5;
  const int f    = w * 32 + n32;

  // A-frags: 16 contiguous b128 loads
  bf16x8 a[16];
#pragma unroll
  for (int ks = 0; ks < 16; ks++)
    a[ks] = *(const bf16x8*)&updT[f * 256 + ks * 16 + hi * 8];

  const int nT = BN >> 5;
  int par = 0;
  for (int tile = blockIdx.x; tile < nT; tile += gridDim.x, par ^= 1) {
    const int row  = tile * 32 + n32;
    const int b    = (row >= NN) ? 1 : 0;
    const int node = row - b * NN;
    const size_t hrow = (size_t)row * DD;
    const size_t arow = (size_t)node * 256 + b * 128;

    bf16x8 bf[16];
#pragma unroll
    for (int ks = 0; ks < 8; ks++) {
      const float4 x0 = *(const float4*)(h + hrow + ks * 16 + hi * 8);
      const float4 x1 = *(const float4*)(h + hrow + ks * 16 + hi * 8 + 4);
      FragU u;
      *(unsigned*)&u.u[0] = pk2bf(x0.x, x0.y);
      *(unsigned*)&u.u[2] = pk2bf(x0.z, x0.w);
      *(unsigned*)&u.u[4] = pk2bf(x1.x, x1.y);
      *(unsigned*)&u.u[6] = pk2bf(x1.z, x1.w);
      bf[ks] = u.v;
    }
#pragma unroll
    for (int ks = 8; ks < 16; ks++)
      bf[ks] = *(const bf16x8*)(h_agg + arow + (ks - 8) * 16 + hi * 8);

    f32x16 acc = (f32x16)0.f;
#pragma unroll
    for (int ks = 0; ks < 16; ks++)
      acc = __builtin_amdgcn_mfma_f32_32x32x16_bf16(a[ks], bf[ks], acc, 0, 0, 0);

    // epilogue: x = h + relu(upd + bias); LN over f (cross-wave via LDS)
    float xv[16];
    float s1 = 0.f, s2 = 0.f;
#pragma unroll
    for (int q = 0; q < 4; q++) {
      const int f0 = w * 32 + q * 8 + hi * 4;
      const float4 bv = *(const float4*)(upd_b + f0);
      const float4 hv = *(const float4*)(h + hrow + f0);
      float x0 = hv.x + fmaxf(acc[q * 4 + 0] + bv.x, 0.f);
      float x1 = hv.y + fmaxf(acc[q * 4 + 1] + bv.y, 0.f);
      float x2 = hv.z + fmaxf(acc[q * 4 + 2] + bv.z, 0.f);
      float x3 = hv.w + fmaxf(acc[q * 4 + 3] + bv.w, 0.f);
      xv[q * 4 + 0] = x0; xv[q * 4 + 1] = x1;
      xv[q * 4 + 2] = x2; xv[q * 4 + 3] = x3;
      s1 += x0 + x1 + x2 + x3;
      s2 += x0 * x0 + x1 * x1 + x2 * x2 + x3 * x3;
    }
    s1 += __shfl_xor(s1, 32, 64);
    s2 += __shfl_xor(s2, 32, 64);
    if (hi == 0) red[par][w][n32] = float2{s1, s2};
    __syncthreads();
    float t1 = 0.f, t2 = 0.f;
#pragma unroll
    for (int ww = 0; ww < 4; ww++) {
      const float2 r = red[par][ww][n32];
      t1 += r.x; t2 += r.y;
    }
    const float mu   = t1 * (1.0f / DD);
    const float var  = t2 * (1.0f / DD) - mu * mu;
    const float rstd = rsqrtf(var + LN_EPS);

#pragma unroll
    for (int q = 0; q < 4; q++) {
      const int f0 = w * 32 + q * 8 + hi * 4;
      const float4 gv = *(const float4*)(gamma + f0);
      const float4 bt = *(const float4*)(beta + f0);
      float4 o;
      o.x = (xv[q * 4 + 0] - mu) * rstd * gv.x + bt.x;
      o.y = (xv[q * 4 + 1] - mu) * rstd * gv.y + bt.y;
      o.z = (xv[q * 4 + 2] - mu) * rstd * gv.z + bt.z;
      o.w = (xv[q * 4 + 3] - mu) * rstd * gv.w + bt.w;
      *(float4*)(out + (size_t)row * DD + f0) = o;
    }
  }
}

// ---------------------------------------------------------------------------
extern "C" void kernel_launch(void* const* d_in, const int* in_sizes, int n_in,
                              void* d_out, int out_size, void* d_ws, size_t ws_size,
                              hipStream_t stream) {
  const float* h       = (const float*)d_in[0];
  const int*   esrc    = (const int*)d_in[1];
  const int*   etgt    = (const int*)d_in[2];
  const int*   erel    = (const int*)d_in[3];
  const float* msg_W   = (const float*)d_in[5];
  const float* rel_emb = (const float*)d_in[6];
  const float* gate_W  = (const float*)d_in[7];
  const float* upd_W   = (const float*)d_in[8];
  const float* upd_b   = (const float*)d_in[9];
  const float* gamma   = (const float*)d_in[10];
  const float* beta    = (const float*)d_in[11];
  float*       out     = (float*)d_out;

  const int BN = in_sizes[0] / DD;   // 100000

  unsigned short* P     = (unsigned short*)d_ws;          // NN*256 bf16
  unsigned short* h_agg = P + (size_t)NN * 256;           // NN*256 bf16
  unsigned short* relb  = h_agg + (size_t)NN * 256;       // RR*128 bf16
  unsigned short* gateT = relb + RR * DD;                 // 128*128 bf16
  unsigned short* msgT  = gateT + 128 * 128;              // 128*128 bf16
  unsigned short* updT  = msgT + 128 * 128;               // 128*256 bf16
  int* deg    = (int*)(updT + 128 * 256);
  int* rstart = deg + NN;
  int* cur    = rstart + NN;
  int* bsum   = cur + NN;
  int* boff   = bsum + 256;
  int* packed = boff + 256;                               // EE ints

  const int nbN = (NN + 255) / 256;
  const int nbE = (EE + 255) / 256;

  k_prep<<<nbN, 256, 0, stream>>>(rel_emb, gate_W, msg_W, upd_W,
                                  relb, gateT, msgT, updT, deg);

  k_node<<<1024, 256, 0, stream>>>(h, gateT, msgT, P, BN);

  k_hist<<<nbE, 256, 0, stream>>>(etgt, deg);
  k_scan_block<<<nbN, 256, 0, stream>>>(deg, rstart, bsum, NN);
  k_scan_small<<<1, 256, 0, stream>>>(bsum, boff, nbN);
  k_add_off<<<nbN, 256, 0, stream>>>(rstart, boff, cur, NN);
  k_fill<<<nbE, 256, 0, stream>>>(esrc, etgt, erel, cur, packed);

  k_agg<<<(NN + 3) / 4, 256, 0, stream>>>(P, relb, rstart, packed, h_agg);

  k_update_ln<<<1024, 256, 0, stream>>>(h, h_agg, updT, upd_b,
                                        gamma, beta, out, BN);
}

// Round 9
// 292.961 us; speedup vs baseline: 1.0525x; 1.0525x over previous
//
#include <hip/hip_runtime.h>

#define DD 128
#define NN 50000      // nodes (N)
#define BB 2          // batch
#define EE 500000     // edges
#define RR 500        // relations
#define LN_EPS 1e-5f

typedef __attribute__((ext_vector_type(8))) short bf16x8;
typedef __attribute__((ext_vector_type(16))) float f32x16;

union FragU { unsigned short u[8]; bf16x8 v; };

__device__ __forceinline__ unsigned short f2bf(float x) {
  union { float f; unsigned u; } v; v.f = x;
  unsigned r = (v.u + 0x7FFFu + ((v.u >> 16) & 1u)) >> 16;
  return (unsigned short)r;
}

#if defined(__has_builtin)
#if __has_builtin(__builtin_amdgcn_cvt_pk_bf16_f32)
#define HAVE_PK_BF16 1
#endif
#endif
__device__ __forceinline__ unsigned pk2bf(float a, float b) {
#ifdef HAVE_PK_BF16
  typedef __attribute__((ext_vector_type(2))) __bf16 bf16x2_t;
  union { bf16x2_t v; unsigned u; } c;
  c.v = __builtin_amdgcn_cvt_pk_bf16_f32(a, b);
  return c.u;
#else
  return (unsigned)f2bf(a) | ((unsigned)f2bf(b) << 16);
#endif
}

__device__ __forceinline__ float bfbits(unsigned short s) {
  union { unsigned u; float f; } v;
  v.u = ((unsigned)s) << 16;
  return v.f;
}
__device__ __forceinline__ float sigmoidf(float x) {
  return 1.0f / (1.0f + __expf(-x));
}

// ---------------------------------------------------------------------------
// k_prep: zero deg + global counter; rel_emb -> bf16; transpose+convert the
// 3 weight matrices to bf16 [f][k] (contiguous A-frag preloads).
// ---------------------------------------------------------------------------
__global__ __launch_bounds__(256) void k_prep(
    const float* __restrict__ rel_emb, const float* __restrict__ gate_W,
    const float* __restrict__ msg_W, const float* __restrict__ upd_W,
    unsigned short* __restrict__ relb, unsigned short* __restrict__ gateT,
    unsigned short* __restrict__ msgT, unsigned short* __restrict__ updT,
    int* __restrict__ deg, int* __restrict__ counter)
{
  const int id = blockIdx.x * 256 + threadIdx.x;
  if (id == 0) *counter = 0;
  if (id < RR * DD / 2)
    *(unsigned*)&relb[2 * id] = pk2bf(rel_emb[2 * id], rel_emb[2 * id + 1]);
  if (id < NN) deg[id] = 0;
  if (id < 128 * 64) {               // gate + msg: f = id>>6, k2 = id&63
    const int f = id >> 6, k2 = id & 63;
    *(unsigned*)&gateT[f * 128 + 2 * k2] =
        pk2bf(gate_W[(2 * k2) * DD + f], gate_W[(2 * k2 + 1) * DD + f]);
    *(unsigned*)&msgT[f * 128 + 2 * k2] =
        pk2bf(msg_W[(2 * k2) * DD + f], msg_W[(2 * k2 + 1) * DD + f]);
  }
  if (id < 128 * 128) {              // upd: f = id>>7, k2 = id&127 (K=256)
    const int f = id >> 7, k2 = id & 127;
    *(unsigned*)&updT[f * 256 + 2 * k2] =
        pk2bf(upd_W[(2 * k2) * DD + f], upd_W[(2 * k2 + 1) * DD + f]);
  }
}

// ---------------------------------------------------------------------------
// k_conv: streaming h (fp32) -> hb (bf16). 8 floats per thread.
// ---------------------------------------------------------------------------
__global__ __launch_bounds__(256) void k_conv(
    const float* __restrict__ h, unsigned short* __restrict__ hb, int n8)
{
  for (int i = blockIdx.x * 256 + threadIdx.x; i < n8; i += gridDim.x * 256) {
    const float4 x0 = *(const float4*)(h + (size_t)i * 8);
    const float4 x1 = *(const float4*)(h + (size_t)i * 8 + 4);
    uint4 o;
    o.x = pk2bf(x0.x, x0.y);
    o.y = pk2bf(x0.z, x0.w);
    o.z = pk2bf(x1.x, x1.y);
    o.w = pk2bf(x1.z, x1.w);
    *(uint4*)(hb + (size_t)i * 8) = o;
  }
}

// ---------------------------------------------------------------------------
// Kernel 1: node dual-GEMM, 32x32x16 MFMA, weights register-resident.
// B-frags direct b128 from hb; next tile prefetched before current MFMA.
// P staged through parity LDS -> full-128B-line cooperative stores.
// ---------------------------------------------------------------------------
__global__ __launch_bounds__(256, 2) void k_node(
    const unsigned short* __restrict__ hb,
    const unsigned short* __restrict__ gateT,
    const unsigned short* __restrict__ msgT, unsigned short* __restrict__ P,
    int BN)
{
  __shared__ unsigned short Ps[2][32][132];

  const int t    = threadIdx.x;
  const int w    = t >> 6;
  const int lane = t & 63;
  const int n32  = lane & 31;
  const int hi   = lane >> 5;
  const int f    = w * 32 + n32;

  bf16x8 ag[8], am[8];
#pragma unroll
  for (int ks = 0; ks < 8; ks++) {
    ag[ks] = *(const bf16x8*)&gateT[f * 128 + ks * 16 + hi * 8];
    am[ks] = *(const bf16x8*)&msgT [f * 128 + ks * 16 + hi * 8];
  }

  const int nodeL = t >> 3;
  const int ch    = t & 7;
  const int nT    = BN >> 5;

  int tile = blockIdx.x;
  bf16x8 bc[8];
  if (tile < nT) {
    const size_t hoff = (size_t)(tile * 32 + n32) * DD + hi * 8;
#pragma unroll
    for (int ks = 0; ks < 8; ks++)
      bc[ks] = *(const bf16x8*)(hb + hoff + ks * 16);
  }

  int par = 0;
  for (; tile < nT; tile += gridDim.x, par ^= 1) {
    // prefetch next tile's B-frags (overlaps MFMA + epilogue below)
    const int ntile = tile + gridDim.x;
    const size_t poff =
        (size_t)(((ntile < nT) ? ntile : tile) * 32 + n32) * DD + hi * 8;
    bf16x8 bn[8];
#pragma unroll
    for (int ks = 0; ks < 8; ks++)
      bn[ks] = *(const bf16x8*)(hb + poff + ks * 16);

    f32x16 accg = (f32x16)0.f, accm = (f32x16)0.f;
#pragma unroll
    for (int ks = 0; ks < 8; ks++) {
      accg = __builtin_amdgcn_mfma_f32_32x32x16_bf16(ag[ks], bc[ks], accg, 0, 0, 0);
      accm = __builtin_amdgcn_mfma_f32_32x32x16_bf16(am[ks], bc[ks], accm, 0, 0, 0);
    }

    unsigned short* Lr = &Ps[par][n32][w * 32 + hi * 4];
#pragma unroll
    for (int q = 0; q < 4; q++) {
      const float v0 = accm[q * 4 + 0] * sigmoidf(accg[q * 4 + 0]);
      const float v1 = accm[q * 4 + 1] * sigmoidf(accg[q * 4 + 1]);
      const float v2 = accm[q * 4 + 2] * sigmoidf(accg[q * 4 + 2]);
      const float v3 = accm[q * 4 + 3] * sigmoidf(accg[q * 4 + 3]);
      uint2 o;
      o.x = pk2bf(v0, v1);
      o.y = pk2bf(v2, v3);
      *(uint2*)(Lr + q * 8) = o;
    }
    __syncthreads();

    const int grow = tile * 32 + nodeL;
    const int bS   = (grow >= NN) ? 1 : 0;
    unsigned short* gp = P + (size_t)(grow - bS * NN) * 256 + bS * 128;
    *(uint4*)(gp + ch * 8)       = *(uint4*)&Ps[par][nodeL][ch * 8];
    *(uint4*)(gp + (ch + 8) * 8) = *(uint4*)&Ps[par][nodeL][(ch + 8) * 8];

#pragma unroll
    for (int ks = 0; ks < 8; ks++) bc[ks] = bn[ks];
  }
}

// ---------------------------------------------------------------------------
// CSR build: histogram -> one-kernel offsets (wave scan + global atomic,
// segments disjoint/contiguous but node order arbitrary) -> fill.
// ---------------------------------------------------------------------------
__global__ __launch_bounds__(256) void k_hist(
    const int* __restrict__ etgt, int* __restrict__ deg)
{
  const int e = blockIdx.x * 256 + threadIdx.x;
  if (e < EE) atomicAdd(&deg[etgt[e]], 1);
}

__global__ __launch_bounds__(256) void k_offsets(
    const int* __restrict__ deg, int* __restrict__ rstart,
    int* __restrict__ cur, int* __restrict__ counter)
{
  const int i    = blockIdx.x * 256 + threadIdx.x;
  const int lane = threadIdx.x & 63;
  const int d    = (i < NN) ? deg[i] : 0;

  int s = d;                         // inclusive wave scan
#pragma unroll
  for (int off = 1; off < 64; off <<= 1) {
    const int tv = __shfl_up(s, off, 64);
    if (lane >= off) s += tv;
  }
  int base = 0;
  if (lane == 63) base = atomicAdd(counter, s);   // s on lane63 = wave total
  base = __shfl(base, 63, 64);
  if (i < NN) {
    const int v = base + s - d;
    rstart[i] = v;
    cur[i] = v;
  }
}

__global__ __launch_bounds__(256) void k_fill(
    const int* __restrict__ esrc, const int* __restrict__ etgt,
    const int* __restrict__ erel, int* __restrict__ cur,
    int* __restrict__ packed)
{
  const int e = blockIdx.x * 256 + threadIdx.x;
  if (e < EE) {
    const int pos = atomicAdd(&cur[etgt[e]], 1);
    packed[pos] = esrc[e] | (erel[e] << 16);
  }
}

// ---------------------------------------------------------------------------
// Kernel 2: gather aggregation. One wave per node; half-wave per edge,
// 4x unrolled. end = beg + deg (segments not node-ordered).
// ---------------------------------------------------------------------------
__global__ __launch_bounds__(256) void k_agg(
    const unsigned short* __restrict__ P, const unsigned short* __restrict__ relb,
    const int* __restrict__ rstart, const int* __restrict__ deg,
    const int* __restrict__ packed, unsigned short* __restrict__ h_agg)
{
  const int node = blockIdx.x * 4 + (threadIdx.x >> 6);
  if (node >= NN) return;
  const int lane = threadIdx.x & 63;
  const int half = lane >> 5;
  const int c8   = (lane & 31) * 8;
  const int rc   = c8 & 127;

  const int beg = rstart[node];
  const int end = beg + deg[node];

  float acc[8];
#pragma unroll
  for (int i = 0; i < 8; i++) acc[i] = 0.f;

  int j = beg + half;
  for (; j + 6 < end; j += 8) {
    const int p0 = packed[j];
    const int p1 = packed[j + 2];
    const int p2 = packed[j + 4];
    const int p3 = packed[j + 6];
    const bf16x8 pv0 = *(const bf16x8*)(P + (size_t)(p0 & 0xFFFF) * 256 + c8);
    const bf16x8 rv0 = *(const bf16x8*)(relb + (size_t)(p0 >> 16) * DD + rc);
    const bf16x8 pv1 = *(const bf16x8*)(P + (size_t)(p1 & 0xFFFF) * 256 + c8);
    const bf16x8 rv1 = *(const bf16x8*)(relb + (size_t)(p1 >> 16) * DD + rc);
    const bf16x8 pv2 = *(const bf16x8*)(P + (size_t)(p2 & 0xFFFF) * 256 + c8);
    const bf16x8 rv2 = *(const bf16x8*)(relb + (size_t)(p2 >> 16) * DD + rc);
    const bf16x8 pv3 = *(const bf16x8*)(P + (size_t)(p3 & 0xFFFF) * 256 + c8);
    const bf16x8 rv3 = *(const bf16x8*)(relb + (size_t)(p3 >> 16) * DD + rc);
#pragma unroll
    for (int i = 0; i < 8; i++) {
      acc[i] += bfbits(pv0[i]) * bfbits(rv0[i]);
      acc[i] += bfbits(pv1[i]) * bfbits(rv1[i]);
      acc[i] += bfbits(pv2[i]) * bfbits(rv2[i]);
      acc[i] += bfbits(pv3[i]) * bfbits(rv3[i]);
    }
  }
  for (; j < end; j += 2) {
    const int p0 = packed[j];
    const bf16x8 pv0 = *(const bf16x8*)(P + (size_t)(p0 & 0xFFFF) * 256 + c8);
    const bf16x8 rv0 = *(const bf16x8*)(relb + (size_t)(p0 >> 16) * DD + rc);
#pragma unroll
    for (int i = 0; i < 8; i++) acc[i] += bfbits(pv0[i]) * bfbits(rv0[i]);
  }

#pragma unroll
  for (int i = 0; i < 8; i++) acc[i] += __shfl_xor(acc[i], 32, 64);

  if (half == 0) {
    uint4 o;
    o.x = pk2bf(acc[0], acc[1]);
    o.y = pk2bf(acc[2], acc[3]);
    o.z = pk2bf(acc[4], acc[5]);
    o.w = pk2bf(acc[6], acc[7]);
    *(uint4*)(h_agg + (size_t)node * 256 + c8) = o;
  }
}

// ---------------------------------------------------------------------------
// Kernel 3: update GEMM (K=256), 32x32x16 MFMA, register weights.
// All reads bf16 (hb + h_agg, incl. residual); next tile fully prefetched.
// ---------------------------------------------------------------------------
__global__ __launch_bounds__(256, 2) void k_update_ln(
    const unsigned short* __restrict__ hb,
    const unsigned short* __restrict__ h_agg,
    const unsigned short* __restrict__ updT, const float* __restrict__ upd_b,
    const float* __restrict__ gamma, const float* __restrict__ beta,
    float* __restrict__ out, int BN)
{
  __shared__ float2 red[2][4][32];

  const int t    = threadIdx.x;
  const int w    = t >> 6;
  const int lane = t & 63;
  const int n32  = lane & 31;
  const int hi   = lane >> 5;
  const int f    = w * 32 + n32;

  bf16x8 a[16];
#pragma unroll
  for (int ks = 0; ks < 16; ks++)
    a[ks] = *(const bf16x8*)&updT[f * 256 + ks * 16 + hi * 8];

  const int nT = BN >> 5;
  int tile = blockIdx.x;

  bf16x8 bc[16];
  if (tile < nT) {
    const int row  = tile * 32 + n32;
    const int b    = (row >= NN) ? 1 : 0;
    const size_t hrow = (size_t)row * DD + hi * 8;
    const size_t arow = (size_t)(row - b * NN) * 256 + b * 128 + hi * 8;
#pragma unroll
    for (int ks = 0; ks < 8; ks++)
      bc[ks] = *(const bf16x8*)(hb + hrow + ks * 16);
#pragma unroll
    for (int ks = 8; ks < 16; ks++)
      bc[ks] = *(const bf16x8*)(h_agg + arow + (ks - 8) * 16);
  }

  int par = 0;
  for (; tile < nT; tile += gridDim.x, par ^= 1) {
    const int row  = tile * 32 + n32;
    const size_t hrow = (size_t)row * DD;

    // prefetch next tile's 16 B-frags (overlaps MFMA + epilogue)
    const int ntile = tile + gridDim.x;
    const int prow  = ((ntile < nT) ? ntile : tile) * 32 + n32;
    const int pb    = (prow >= NN) ? 1 : 0;
    const size_t phrow = (size_t)prow * DD + hi * 8;
    const size_t parow = (size_t)(prow - pb * NN) * 256 + pb * 128 + hi * 8;
    bf16x8 bn[16];
#pragma unroll
    for (int ks = 0; ks < 8; ks++)
      bn[ks] = *(const bf16x8*)(hb + phrow + ks * 16);
#pragma unroll
    for (int ks = 8; ks < 16; ks++)
      bn[ks] = *(const bf16x8*)(h_agg + parow + (ks - 8) * 16);

    f32x16 acc = (f32x16)0.f;
#pragma unroll
    for (int ks = 0; ks < 16; ks++)
      acc = __builtin_amdgcn_mfma_f32_32x32x16_bf16(a[ks], bc[ks], acc, 0, 0, 0);

    // epilogue: x = h + relu(upd + bias); LN over f (cross-wave via LDS)
    float xv[16];
    float s1 = 0.f, s2 = 0.f;
#pragma unroll
    for (int q = 0; q < 4; q++) {
      const int f0 = w * 32 + q * 8 + hi * 4;
      const float4 bv = *(const float4*)(upd_b + f0);
      const ushort4 hv = *(const ushort4*)(hb + hrow + f0);
      float x0 = bfbits(hv.x) + fmaxf(acc[q * 4 + 0] + bv.x, 0.f);
      float x1 = bfbits(hv.y) + fmaxf(acc[q * 4 + 1] + bv.y, 0.f);
      float x2 = bfbits(hv.z) + fmaxf(acc[q * 4 + 2] + bv.z, 0.f);
      float x3 = bfbits(hv.w) + fmaxf(acc[q * 4 + 3] + bv.w, 0.f);
      xv[q * 4 + 0] = x0; xv[q * 4 + 1] = x1;
      xv[q * 4 + 2] = x2; xv[q * 4 + 3] = x3;
      s1 += x0 + x1 + x2 + x3;
      s2 += x0 * x0 + x1 * x1 + x2 * x2 + x3 * x3;
    }
    s1 += __shfl_xor(s1, 32, 64);
    s2 += __shfl_xor(s2, 32, 64);
    if (hi == 0) red[par][w][n32] = float2{s1, s2};
    __syncthreads();
    float t1 = 0.f, t2 = 0.f;
#pragma unroll
    for (int ww = 0; ww < 4; ww++) {
      const float2 r = red[par][ww][n32];
      t1 += r.x; t2 += r.y;
    }
    const float mu   = t1 * (1.0f / DD);
    const float var  = t2 * (1.0f / DD) - mu * mu;
    const float rstd = rsqrtf(var + LN_EPS);

#pragma unroll
    for (int q = 0; q < 4; q++) {
      const int f0 = w * 32 + q * 8 + hi * 4;
      const float4 gv = *(const float4*)(gamma + f0);
      const float4 bt = *(const float4*)(beta + f0);
      float4 o;
      o.x = (xv[q * 4 + 0] - mu) * rstd * gv.x + bt.x;
      o.y = (xv[q * 4 + 1] - mu) * rstd * gv.y + bt.y;
      o.z = (xv[q * 4 + 2] - mu) * rstd * gv.z + bt.z;
      o.w = (xv[q * 4 + 3] - mu) * rstd * gv.w + bt.w;
      *(float4*)(out + hrow + f0) = o;
    }

#pragma unroll
    for (int ks = 0; ks < 16; ks++) bc[ks] = bn[ks];
  }
}

// ---------------------------------------------------------------------------
extern "C" void kernel_launch(void* const* d_in, const int* in_sizes, int n_in,
                              void* d_out, int out_size, void* d_ws, size_t ws_size,
                              hipStream_t stream) {
  const float* h       = (const float*)d_in[0];
  const int*   esrc    = (const int*)d_in[1];
  const int*   etgt    = (const int*)d_in[2];
  const int*   erel    = (const int*)d_in[3];
  const float* msg_W   = (const float*)d_in[5];
  const float* rel_emb = (const float*)d_in[6];
  const float* gate_W  = (const float*)d_in[7];
  const float* upd_W   = (const float*)d_in[8];
  const float* upd_b   = (const float*)d_in[9];
  const float* gamma   = (const float*)d_in[10];
  const float* beta    = (const float*)d_in[11];
  float*       out     = (float*)d_out;

  const int BN = in_sizes[0] / DD;   // 100000

  unsigned short* P     = (unsigned short*)d_ws;          // NN*256 bf16
  unsigned short* h_agg = P + (size_t)NN * 256;           // NN*256 bf16
  unsigned short* hb    = h_agg + (size_t)NN * 256;       // BN*128 bf16
  unsigned short* relb  = hb + (size_t)BN * DD;           // RR*128 bf16
  unsigned short* gateT = relb + RR * DD;                 // 128*128 bf16
  unsigned short* msgT  = gateT + 128 * 128;              // 128*128 bf16
  unsigned short* updT  = msgT + 128 * 128;               // 128*256 bf16
  int* deg     = (int*)(updT + 128 * 256);
  int* rstart  = deg + NN;
  int* cur     = rstart + NN;
  int* counter = cur + NN;                                // 1
  int* packed  = counter + 1;                             // EE ints

  const int nbN = (NN + 255) / 256;
  const int nbE = (EE + 255) / 256;

  k_prep<<<nbN, 256, 0, stream>>>(rel_emb, gate_W, msg_W, upd_W,
                                  relb, gateT, msgT, updT, deg, counter);

  k_conv<<<2048, 256, 0, stream>>>(h, hb, BN * DD / 8);

  k_node<<<1024, 256, 0, stream>>>(hb, gateT, msgT, P, BN);

  k_hist<<<nbE, 256, 0, stream>>>(etgt, deg);
  k_offsets<<<nbN, 256, 0, stream>>>(deg, rstart, cur, counter);
  k_fill<<<nbE, 256, 0, stream>>>(esrc, etgt, erel, cur, packed);

  k_agg<<<(NN + 3) / 4, 256, 0, stream>>>(P, relb, rstart, deg, packed, h_agg);

  k_update_ln<<<512, 256, 0, stream>>>(hb, h_agg, updT, upd_b,
                                       gamma, beta, out, BN);
}